// Round 8
// baseline (1977.602 us; speedup 1.0000x reference)
//
#include <hip/hip_runtime.h>
#include <hip/hip_bf16.h>

// RecurrentEntityNetwork on MI355X. S=128, B=1024, DOBJ=37, QD=11, D=256, M=20.
// Dual-dtype (runtime probe on prelu_a bits): inputs either bf16 or f32.
// phase1: mi = relu(MI@C^T+Cb) -> ws ; jv = relu(mi@V^T+Vb)@J2^T -> ws
// recur : 512 WGs x 1024 thr (16 waves, 16-col resident weight slices, 4
//         waves/SIMD). Transposed GEMMs, b64 epilogue. R8: HW packed bf16
//         cvt (v_cvt_pk_bf16_f32), Jb folded into JWL, jw + old-mem carried
//         in registers across steps, vectorized jv staging.

#define S_LEN 128
#define BSZ   1024
#define DOBJ  37
#define QD    11

typedef float f32x4 __attribute__((ext_vector_type(4)));
typedef short bf16x8 __attribute__((ext_vector_type(8)));
typedef short bf16x4 __attribute__((ext_vector_type(4)));

#define MFMA16(a, b, c) __builtin_amdgcn_mfma_f32_16x16x32_bf16((a), (b), (c), 0, 0, 0)

__device__ __forceinline__ float b2f(short h) {
    union { unsigned u; float f; } c; c.u = ((unsigned)(unsigned short)h) << 16; return c.f;
}
__device__ __forceinline__ short f2b(float x) {   // f32 -> bf16 RNE (scalar, init paths)
    union { float f; unsigned u; } c; c.f = x;
    return (short)((c.u + 0x7FFFu + ((c.u >> 16) & 1u)) >> 16);
}
__device__ __forceinline__ unsigned pkbf(float a, float b) {  // HW v_cvt_pk_bf16_f32
    union { __hip_bfloat162 h2; unsigned u; } c;
    c.h2 = __float22bfloat162_rn(make_float2(a, b));
    return c.u;
}
__device__ __forceinline__ float ld1(const void* p, int i, bool f32) {
    return f32 ? ((const float*)p)[i] : b2f(((const short*)p)[i]);
}
__device__ __forceinline__ bf16x8 ld8(const void* p, int i, bool f32) {  // i: 8-elem aligned
    if (!f32) return *(const bf16x8*)((const short*)p + i);
    const float* q = (const float*)p + i;
    bf16x8 r;
    #pragma unroll
    for (int e = 0; e < 8; ++e) r[e] = f2b(q[e]);
    return r;
}

// ---------------------------------------------------------------------------
// Phase 1: mi and jv for all (s,b). 64 rows/WG, grid 2048.  (unchanged)
// ---------------------------------------------------------------------------
__global__ __launch_bounds__(256, 2) void renet_phase1(
    const void* __restrict__ MI, const void* __restrict__ Cw, const void* __restrict__ Cb,
    const void* __restrict__ Vw, const void* __restrict__ Vb, const void* __restrict__ Jw,
    const void* __restrict__ PA, short* __restrict__ mi_out, short* __restrict__ jv_out)
{
    const bool F32 = (*(const unsigned*)PA == 0x3F800000u);
    __shared__ __align__(16) short A[64 * 264];
    __shared__ __align__(16) float MIL[64 * 40];
    __shared__ float VBL[256];

    const int t = threadIdx.x, r0 = blockIdx.x * 64;
    const int wv = t >> 6, lane = t & 63, lr = lane & 15, quad = lane >> 4;

    VBL[t] = ld1(Vb, t, F32);
    for (int c = 0; c < 10; ++c) {
        int idx = c * 256 + t;
        if (idx < 64 * 37) { int i = idx / 37, k = idx - i * 37; MIL[i * 40 + k] = ld1(MI, (r0 + i) * 37 + k, F32); }
    }
    __syncthreads();

    {   // mi = relu(MI @ Cw^T + Cb), column t; also store to ws
        float cw[DOBJ];
        #pragma unroll
        for (int k = 0; k < DOBJ; ++k) cw[k] = ld1(Cw, t * DOBJ + k, F32);
        float cb = ld1(Cb, t, F32);
        for (int i = 0; i < 64; ++i) {
            float a = cb;
            #pragma unroll
            for (int k = 0; k < DOBJ; ++k) a += MIL[i * 40 + k] * cw[k];
            short h = f2b(fmaxf(a, 0.f));
            A[i * 264 + t] = h;
            mi_out[(r0 + i) * 256 + t] = h;
        }
    }
    __syncthreads();

    const f32x4 Z4 = {0.f, 0.f, 0.f, 0.f};
    f32x4 acc[4][4];

    // v = mi @ Vw^T
    #pragma unroll
    for (int rt = 0; rt < 4; ++rt)
        #pragma unroll
        for (int nt = 0; nt < 4; ++nt) acc[rt][nt] = Z4;
    #pragma unroll
    for (int kt = 0; kt < 8; ++kt) {
        bf16x8 a[4];
        #pragma unroll
        for (int rt = 0; rt < 4; ++rt)
            a[rt] = *(const bf16x8*)&A[(rt * 16 + lr) * 264 + kt * 32 + quad * 8];
        #pragma unroll
        for (int nt = 0; nt < 4; ++nt) {
            int n = wv * 64 + nt * 16 + lr;
            bf16x8 b = ld8(Vw, n * 256 + kt * 32 + quad * 8, F32);
            #pragma unroll
            for (int rt = 0; rt < 4; ++rt) acc[rt][nt] = MFMA16(a[rt], b, acc[rt][nt]);
        }
    }
    __syncthreads();
    #pragma unroll
    for (int nt = 0; nt < 4; ++nt) {
        int n = wv * 64 + nt * 16 + lr;
        float vb = VBL[n];
        #pragma unroll
        for (int rt = 0; rt < 4; ++rt)
            #pragma unroll
            for (int r = 0; r < 4; ++r)
                A[(rt * 16 + quad * 4 + r) * 264 + n] = f2b(fmaxf(acc[rt][nt][r] + vb, 0.f));
    }
    __syncthreads();

    // jv = relu_v @ J2^T (J2 = Jw[:,256:512])
    #pragma unroll
    for (int rt = 0; rt < 4; ++rt)
        #pragma unroll
        for (int nt = 0; nt < 4; ++nt) acc[rt][nt] = Z4;
    #pragma unroll
    for (int kt = 0; kt < 8; ++kt) {
        bf16x8 a[4];
        #pragma unroll
        for (int rt = 0; rt < 4; ++rt)
            a[rt] = *(const bf16x8*)&A[(rt * 16 + lr) * 264 + kt * 32 + quad * 8];
        #pragma unroll
        for (int nt = 0; nt < 4; ++nt) {
            int n = wv * 64 + nt * 16 + lr;
            bf16x8 b = ld8(Jw, n * 768 + 256 + kt * 32 + quad * 8, F32);
            #pragma unroll
            for (int rt = 0; rt < 4; ++rt) acc[rt][nt] = MFMA16(a[rt], b, acc[rt][nt]);
        }
    }
    __syncthreads();
    #pragma unroll
    for (int nt = 0; nt < 4; ++nt) {
        int n = wv * 64 + nt * 16 + lr;
        #pragma unroll
        for (int rt = 0; rt < 4; ++rt)
            #pragma unroll
            for (int r = 0; r < 4; ++r)
                A[(rt * 16 + quad * 4 + r) * 264 + n] = f2b(acc[rt][nt][r]);
    }
    __syncthreads();
    for (int c = 0; c < 16; ++c) {
        int idx = c * 1024 + t * 4;
        int i = idx >> 8, k = idx & 255;
        *(ushort4*)&jv_out[(r0 + i) * 256 + k] = *(const ushort4*)&A[i * 264 + k];
    }
}

// ---------------------------------------------------------------------------
// Recurrence + head. grid 512 x 1024 thr (16 waves), 2 batches/WG.
// LDS 65472 B:
//   A1 [60*264] rows 0..39 mem, 40..59 keys; pad: col256-259 = RS double-buf
//                (f32 x2), col260-263 = gate logits (f32 x2, [bi])
//   STG[40*264] relu_u restage + head scratch
//   SJ [ 4*264] rows 0-1 sent(mi), rows 2-3 jv RAW (Jb folded into JWL)
//   JWL[20*264] key-path J contribution + Jb, [slot][col] bf16
// ---------------------------------------------------------------------------
__global__ __launch_bounds__(1024) void renet_recur(
    const short* __restrict__ mi, const short* __restrict__ jv,
    const void* __restrict__ Qin, const void* __restrict__ Qw, const void* __restrict__ Qb,
    const void* __restrict__ Uw, const void* __restrict__ Ub,
    const void* __restrict__ Jw, const void* __restrict__ Jb,
    const void* __restrict__ Ww, const void* __restrict__ Wb,
    const void* __restrict__ Hw, const void* __restrict__ Hb,
    const void* __restrict__ PA, const void* __restrict__ Emb, void* __restrict__ Out)
{
    const bool F32 = (*(const unsigned*)PA == 0x3F800000u);
    __shared__ __align__(16) short LDS[32736];    // 65472 B
    short* const A1  = LDS;            // 60*264 = 15840 shorts
    short* const STG = LDS + 15840;    // 40*264 = 10560
    short* const SJ  = LDS + 26400;    //  4*264 =  1056
    short* const JWL = LDS + 27456;    // 20*264 =  5280  (end 32736)

    const int t = threadIdx.x;                 // 0..1023
    const int w16 = t >> 6;                    // wave 0..15
    const int lane = t & 63, lr = lane & 15, quad = lane >> 4;
    const int colb = w16 * 16;                 // this wave's 16-col slice
    const int col4 = colb + quad * 4;          // lane's 4-col group
    const float pa = ld1(PA, 0, F32);
    const f32x4 Z4 = {0.f, 0.f, 0.f, 0.f};
    const int bq0 = blockIdx.x * 2;

    float ub2[4];
    #pragma unroll
    for (int r = 0; r < 4; ++r) ub2[r] = ld1(Ub, col4 + r, F32);

    // resident weight fragments (A-operand layout, lane lr = weight row)
    bf16x8 uf[8], jf[8];
    #pragma unroll
    for (int kt = 0; kt < 8; ++kt) {
        uf[kt] = ld8(Uw, (colb + lr) * 256 + kt * 32 + quad * 8, F32);
        jf[kt] = ld8(Jw, (colb + lr) * 768 + kt * 32 + quad * 8, F32);
    }

    // keys -> A1 rows 40..59 (pads zeroed)
    for (int c = 0; c < 6; ++c) {
        int idx = c * 1024 + t;
        if (idx < 20 * 264) {
            int row = idx / 264, k = idx - row * 264;
            A1[(40 + row) * 264 + k] = (k < 256) ? f2b(ld1(Emb, row * 256 + k, F32)) : (short)0;
        }
    }
    __syncthreads();

    // WKS = relu(Emb@Ww^T+Wb) (f32 in STG) ; mem init in parallel
    {
        const int col = t & 255, grp = t >> 8, m0p = grp * 5;
        float* WKS = (float*)STG;
        float wacc[5] = {0.f, 0.f, 0.f, 0.f, 0.f};
        for (int c = 0; c < 32; ++c) {
            bf16x8 wv8 = ld8(Ww, col * 256 + c * 8, F32);
            float wf[8];
            #pragma unroll
            for (int e = 0; e < 8; ++e) wf[e] = b2f(wv8[e]);
            #pragma unroll
            for (int mm = 0; mm < 5; ++mm) {
                bf16x8 e8 = *(const bf16x8*)&A1[(40 + m0p + mm) * 264 + c * 8];
                float s = 0.f;
                #pragma unroll
                for (int e = 0; e < 8; ++e) s += b2f(e8[e]) * wf[e];
                wacc[mm] += s;
            }
        }
        float wb = ld1(Wb, col, F32);
        #pragma unroll
        for (int mm = 0; mm < 5; ++mm) WKS[(m0p + mm) * 256 + col] = fmaxf(wacc[mm] + wb, 0.f);
    }
    // mem rows 0..39 = keys (independent of WKS region)
    for (int c = 0; c < 11; ++c) {
        int idx = c * 1024 + t;
        if (idx < 40 * 264) {
            int row = idx / 264, k = idx - row * 264;
            A1[idx] = (k < 256) ? A1[(40 + row % 20) * 264 + k] : (short)0;
        }
    }
    __syncthreads();

    // JWL[slot][col] = (WKS @ J3^T)[slot][col] + Jb[col]   (Jb folded here)
    {
        const int col = t & 255, grp = t >> 8, m0p = grp * 5;
        const float* WKS = (const float*)STG;
        const float jb = ld1(Jb, col, F32);
        float jacc[5] = {0.f, 0.f, 0.f, 0.f, 0.f};
        for (int c = 0; c < 32; ++c) {
            bf16x8 j8 = ld8(Jw, col * 768 + 512 + c * 8, F32);
            float jfv[8];
            #pragma unroll
            for (int e = 0; e < 8; ++e) jfv[e] = b2f(j8[e]);
            #pragma unroll
            for (int mm = 0; mm < 5; ++mm) {
                float4 w0 = *(const float4*)&WKS[(m0p + mm) * 256 + c * 8];
                float4 w1 = *(const float4*)&WKS[(m0p + mm) * 256 + c * 8 + 4];
                jacc[mm] += w0.x * jfv[0] + w0.y * jfv[1] + w0.z * jfv[2] + w0.w * jfv[3]
                          + w1.x * jfv[4] + w1.y * jfv[5] + w1.z * jfv[6] + w1.w * jfv[7];
            }
        }
        #pragma unroll
        for (int mm = 0; mm < 5; ++mm) JWL[(m0p + mm) * 264 + col] = f2b(jacc[mm] + jb);
    }

    // stage s=0: mi rows (t<128, b64) + jv rows raw (128<=t<256, b64); zero RS
    ushort4 pf_mi = {0, 0, 0, 0};
    ushort4 pf_jv = {0, 0, 0, 0};
    if (t < 128) pf_mi = *(const ushort4*)&mi[(bq0 + (t >> 6)) * 256 + (t & 63) * 4];
    else if (t < 256) { int i = t - 128; pf_jv = *(const ushort4*)&jv[(bq0 + (i >> 6)) * 256 + (i & 63) * 4]; }
    if (t < 128) *(ushort4*)&SJ[(t >> 6) * 264 + (t & 63) * 4] = pf_mi;
    else if (t < 256) { int i = t - 128; *(ushort4*)&SJ[(2 + (i >> 6)) * 264 + (i & 63) * 4] = pf_jv; }
    if (t < 40) { *(float*)&A1[t * 264 + 256] = 0.f; *(float*)&A1[t * 264 + 258] = 0.f; }
    __syncthreads();

    // per-tile constants: row, bi, slot; register-resident jw and old-mem
    const int rows_[3] = {lr, 16 + lr, 24 + lr};
    int bi_[3], slot_[3];
    bf16x4 jw_pk[3], mem_pk[3];
    #pragma unroll
    for (int nt = 0; nt < 3; ++nt) {
        int row = rows_[nt];
        int bi = (row >= 20) ? 1 : 0;
        bi_[nt] = bi; slot_[nt] = row - bi * 20;
        jw_pk[nt]  = *(const bf16x4*)&JWL[slot_[nt] * 264 + col4];
        mem_pk[nt] = *(const bf16x4*)&A1[row * 264 + col4];
    }

    for (int s = 0; s < S_LEN; ++s) {
        // prefetch next step's mi/jv (consumed in normalize phase)
        if (s + 1 < S_LEN) {
            if (t < 128) pf_mi = *(const ushort4*)&mi[((s + 1) * BSZ + bq0 + (t >> 6)) * 256 + (t & 63) * 4];
            else if (t < 256) { int i = t - 128; pf_jv = *(const ushort4*)&jv[((s + 1) * BSZ + bq0 + (i >> 6)) * 256 + (i & 63) * 4]; }
        }

        // ---- gate (transposed): G^T = sent(A) x [mem;keys]^T(B), waves 0..3
        if (w16 < 4) {
            const int base = (w16 == 3) ? 44 : w16 * 16;
            f32x4 ag = Z4;
            #pragma unroll
            for (int kt = 0; kt < 8; ++kt) {
                bf16x8 a = *(const bf16x8*)&SJ[lr * 264 + kt * 32 + quad * 8];   // rows>=2 garbage, isolated
                bf16x8 b = *(const bf16x8*)&A1[(base + lr) * 264 + kt * 32 + quad * 8];
                ag = MFMA16(a, b, ag);
            }
            if (quad == 0) {
                float* gl = (float*)&A1[(base + lr) * 264 + 260];
                gl[0] = ag[0]; gl[1] = ag[1];
            }
        }

        // ---- GEMM1 (transposed): u^T = U_slice(A) x mem^T(B)
        f32x4 acc[3];
        acc[0] = Z4; acc[1] = Z4; acc[2] = Z4;
        #pragma unroll
        for (int kt = 0; kt < 8; ++kt) {
            bf16x8 b0 = *(const bf16x8*)&A1[(0 + lr) * 264 + kt * 32 + quad * 8];
            bf16x8 b1 = *(const bf16x8*)&A1[(16 + lr) * 264 + kt * 32 + quad * 8];
            bf16x8 b2 = *(const bf16x8*)&A1[(24 + lr) * 264 + kt * 32 + quad * 8];
            acc[0] = MFMA16(uf[kt], b0, acc[0]);
            acc[1] = MFMA16(uf[kt], b1, acc[1]);
            acc[2] = MFMA16(uf[kt], b2, acc[2]);
        }
        // restage relu(u+Ub): HW packed cvt, b64 write
        #pragma unroll
        for (int nt = 0; nt < 3; ++nt) {
            const int base = (nt == 0) ? 0 : (nt == 1) ? 16 : 24;
            uint2 pk;
            pk.x = pkbf(fmaxf(acc[nt][0] + ub2[0], 0.f), fmaxf(acc[nt][1] + ub2[1], 0.f));
            pk.y = pkbf(fmaxf(acc[nt][2] + ub2[2], 0.f), fmaxf(acc[nt][3] + ub2[3], 0.f));
            *(uint2*)&STG[(base + lr) * 264 + col4] = pk;
        }
        __syncthreads();                                    // B_a

        // ---- GEMM2 (transposed): jU^T = J1_slice(A) x relu_u^T(B)
        f32x4 acc2[3];
        acc2[0] = Z4; acc2[1] = Z4; acc2[2] = Z4;
        #pragma unroll
        for (int kt = 0; kt < 8; ++kt) {
            bf16x8 b0 = *(const bf16x8*)&STG[(0 + lr) * 264 + kt * 32 + quad * 8];
            bf16x8 b1 = *(const bf16x8*)&STG[(16 + lr) * 264 + kt * 32 + quad * 8];
            bf16x8 b2 = *(const bf16x8*)&STG[(24 + lr) * 264 + kt * 32 + quad * 8];
            acc2[0] = MFMA16(jf[kt], b0, acc2[0]);
            acc2[1] = MFMA16(jf[kt], b1, acc2[1]);
            acc2[2] = MFMA16(jf[kt], b2, acc2[2]);
        }

        // ---- epilogue: j -> cand -> upd (jw/old-mem from registers)
        #pragma unroll
        for (int nt = 0; nt < 3; ++nt) {
            const int row = rows_[nt], bi = bi_[nt], slot = slot_[nt];
            float gp = ((const float*)&A1[row * 264 + 260])[bi]
                     + ((const float*)&A1[(40 + slot) * 264 + 260])[bi];
            float gate = 1.f / (1.f + __expf(-gp));
            bf16x4 jv4 = *(const bf16x4*)&SJ[(2 + bi) * 264 + col4];
            float ss = 0.f;
            #pragma unroll
            for (int r = 0; r < 4; ++r) {
                float j = acc2[nt][r] + b2f(jv4[r]) + b2f(jw_pk[nt][r]);
                float cand = j > 0.f ? j : pa * j;
                float u = b2f(mem_pk[nt][r]) + gate * cand;
                acc2[nt][r] = u;
                ss += u * u;
            }
            ss += __shfl_xor(ss, 16);
            ss += __shfl_xor(ss, 32);
            if (quad == 0 && !(nt == 2 && lr < 8))
                atomicAdd((float*)&A1[row * 264 + 256 + ((s & 1) << 1)], ss);
        }
        __syncthreads();                                    // B_b

        // ---- normalize + writeback (HW pk cvt) + stage s+1 + zero RS_next
        #pragma unroll
        for (int nt = 0; nt < 3; ++nt) {
            const int row = rows_[nt];
            float sc = 1.f / (sqrtf(*(const float*)&A1[row * 264 + 256 + ((s & 1) << 1)]) + 1e-12f);
            uint2 pk;
            pk.x = pkbf(acc2[nt][0] * sc, acc2[nt][1] * sc);
            pk.y = pkbf(acc2[nt][2] * sc, acc2[nt][3] * sc);
            mem_pk[nt] = *(bf16x4*)&pk;                     // carry for next epilogue
            *(uint2*)&A1[row * 264 + col4] = pk;
        }
        if (t < 128) *(ushort4*)&SJ[(t >> 6) * 264 + (t & 63) * 4] = pf_mi;
        else if (t < 256) { int i = t - 128; *(ushort4*)&SJ[(2 + (i >> 6)) * 264 + (i & 63) * 4] = pf_jv; }
        if (t < 40) *(float*)&A1[t * 264 + 256 + (((s + 1) & 1) << 1)] = 0.f;
        __syncthreads();                                    // B_c
    }

    // ---------------- attention + output head ----------------
    float* SF = (float*)STG;  // QF[0..511] HC[512..1535] EN[1536..1575] AT[1576..1615]
    if (t < 512) {
        const int col = t & 255, bi = t >> 8;
        float a = ld1(Qb, col, F32);
        #pragma unroll
        for (int k = 0; k < QD; ++k)
            a += ld1(Qin, (bq0 + bi) * QD + k, F32) * ld1(Qw, col * QD + k, F32);
        SF[bi * 256 + col] = fmaxf(a, 0.f);
    }
    __syncthreads();
    if (t < 40) {
        int bi = t / 20;
        float e = 0.f;
        for (int c = 0; c < 32; ++c) {
            bf16x8 mv = *(const bf16x8*)&A1[t * 264 + c * 8];
            #pragma unroll
            for (int e8 = 0; e8 < 8; ++e8) e += b2f(mv[e8]) * SF[bi * 256 + c * 8 + e8];
        }
        SF[1536 + t] = e;
    }
    __syncthreads();
    if (t < 2) {
        float mx = -1e30f;
        for (int m = 0; m < 20; ++m) mx = fmaxf(mx, SF[1536 + t * 20 + m]);
        float sm = 0.f, ex[20];
        for (int m = 0; m < 20; ++m) { ex[m] = __expf(SF[1536 + t * 20 + m] - mx); sm += ex[m]; }
        float inv = 1.f / sm;
        for (int m = 0; m < 20; ++m) SF[1576 + t * 20 + m] = ex[m] * inv;
    }
    __syncthreads();
    if (t < 512) {
        const int col = t & 255, bi = t >> 8;
        float a = 0.f;
        for (int m = 0; m < 20; ++m)
            a += SF[1576 + bi * 20 + m] * b2f(A1[(bi * 20 + m) * 264 + col]);
        SF[512 + bi * 512 + 256 + col] = a;
        SF[512 + bi * 512 + col] = SF[bi * 256 + col];
    }
    __syncthreads();
    if (t < 512) {
        const int col = t & 255, bi = t >> 8;
        float o = ld1(Hb, col, F32);
        for (int c = 0; c < 64; ++c) {
            bf16x8 hv = ld8(Hw, col * 512 + c * 8, F32);
            #pragma unroll
            for (int e8 = 0; e8 < 8; ++e8) o += b2f(hv[e8]) * SF[512 + bi * 512 + c * 8 + e8];
        }
        int oi = (bq0 + bi) * 256 + col;
        float v = fmaxf(o, 0.f);
        if (F32) ((float*)Out)[oi] = v; else ((short*)Out)[oi] = f2b(v);
    }
}

// ---------------------------------------------------------------------------
extern "C" void kernel_launch(void* const* d_in, const int* in_sizes, int n_in,
                              void* d_out, int out_size, void* d_ws, size_t ws_size,
                              hipStream_t stream) {
    (void)in_sizes; (void)n_in; (void)out_size; (void)ws_size;
    const void* MIp = d_in[0];
    const void* Qin = d_in[1];
    const void* Cw  = d_in[2];
    const void* Cb  = d_in[3];
    const void* Qw  = d_in[4];
    const void* Qb  = d_in[5];
    const void* Hw  = d_in[6];
    const void* Hb  = d_in[7];
    const void* Uw  = d_in[8];
    const void* Ub  = d_in[9];
    const void* Vw  = d_in[10];
    const void* Vb  = d_in[11];
    const void* Ww  = d_in[12];
    const void* Wb  = d_in[13];
    const void* Jw  = d_in[14];
    const void* Jb  = d_in[15];
    const void* PA  = d_in[16];
    const void* Emb = d_in[17];

    short* mi_ws = (short*)d_ws;                          // (S*B,256) bf16 = 64 MiB
    short* jv_ws = mi_ws + (size_t)S_LEN * BSZ * 256;     // (S*B,256) bf16 = 64 MiB

    renet_phase1<<<dim3(2048), dim3(256), 0, stream>>>(MIp, Cw, Cb, Vw, Vb, Jw, PA, mi_ws, jv_ws);
    renet_recur<<<dim3(512), dim3(1024), 0, stream>>>(mi_ws, jv_ws, Qin, Qw, Qb, Uw, Ub,
                                                      Jw, Jb, Ww, Wb, Hw, Hb, PA, Emb, d_out);
}

// Round 10
// 1840.286 us; speedup vs baseline: 1.0746x; 1.0746x over previous
//
#include <hip/hip_runtime.h>
#include <hip/hip_bf16.h>

// RecurrentEntityNetwork on MI355X. S=128, B=1024, DOBJ=37, QD=11, D=256, M=20.
// Dual-dtype (runtime probe on prelu_a bits): inputs either bf16 or f32.
// phase1: mi = relu(MI@C^T+Cb) -> ws ; jv = relu(mi@V^T+Vb)@J2^T -> ws
// recur : 512 WGs x 1024 thr (16 waves, 16-col resident weight slices;
//         4 waves/SIMD hard cap). DEFERRED NORMALIZATION (mem raw + RS,
//         scale applied lazily) -> 2 barriers/step.
//   R10 fix: epilogue split gather->commit. R9 merged writeback into the
//   epilogue loop, racing on duplicated tile rows 24-31 (lane8 nt=1 write
//   before lane0 nt=2 old-mem read). All LDS reads now precede all writes.

#define S_LEN 128
#define BSZ   1024
#define DOBJ  37
#define QD    11

typedef float f32x4 __attribute__((ext_vector_type(4)));
typedef short bf16x8 __attribute__((ext_vector_type(8)));
typedef short bf16x4 __attribute__((ext_vector_type(4)));

#define MFMA16(a, b, c) __builtin_amdgcn_mfma_f32_16x16x32_bf16((a), (b), (c), 0, 0, 0)

__device__ __forceinline__ float b2f(short h) {
    union { unsigned u; float f; } c; c.u = ((unsigned)(unsigned short)h) << 16; return c.f;
}
__device__ __forceinline__ short f2b(float x) {   // f32 -> bf16 RNE (init paths)
    union { float f; unsigned u; } c; c.f = x;
    return (short)((c.u + 0x7FFFu + ((c.u >> 16) & 1u)) >> 16);
}
__device__ __forceinline__ unsigned pkbf(float a, float b) {  // HW v_cvt_pk_bf16_f32
    union { __hip_bfloat162 h2; unsigned u; } c;
    c.h2 = __float22bfloat162_rn(make_float2(a, b));
    return c.u;
}
__device__ __forceinline__ float ld1(const void* p, int i, bool f32) {
    return f32 ? ((const float*)p)[i] : b2f(((const short*)p)[i]);
}
__device__ __forceinline__ bf16x8 ld8(const void* p, int i, bool f32) {  // i: 8-elem aligned
    if (!f32) return *(const bf16x8*)((const short*)p + i);
    const float* q = (const float*)p + i;
    bf16x8 r;
    #pragma unroll
    for (int e = 0; e < 8; ++e) r[e] = f2b(q[e]);
    return r;
}

// ---------------------------------------------------------------------------
// Phase 1: mi and jv for all (s,b). 64 rows/WG, grid 2048.  (unchanged)
// ---------------------------------------------------------------------------
__global__ __launch_bounds__(256, 2) void renet_phase1(
    const void* __restrict__ MI, const void* __restrict__ Cw, const void* __restrict__ Cb,
    const void* __restrict__ Vw, const void* __restrict__ Vb, const void* __restrict__ Jw,
    const void* __restrict__ PA, short* __restrict__ mi_out, short* __restrict__ jv_out)
{
    const bool F32 = (*(const unsigned*)PA == 0x3F800000u);
    __shared__ __align__(16) short A[64 * 264];
    __shared__ __align__(16) float MIL[64 * 40];
    __shared__ float VBL[256];

    const int t = threadIdx.x, r0 = blockIdx.x * 64;
    const int wv = t >> 6, lane = t & 63, lr = lane & 15, quad = lane >> 4;

    VBL[t] = ld1(Vb, t, F32);
    for (int c = 0; c < 10; ++c) {
        int idx = c * 256 + t;
        if (idx < 64 * 37) { int i = idx / 37, k = idx - i * 37; MIL[i * 40 + k] = ld1(MI, (r0 + i) * 37 + k, F32); }
    }
    __syncthreads();

    {   // mi = relu(MI @ Cw^T + Cb), column t; also store to ws
        float cw[DOBJ];
        #pragma unroll
        for (int k = 0; k < DOBJ; ++k) cw[k] = ld1(Cw, t * DOBJ + k, F32);
        float cb = ld1(Cb, t, F32);
        for (int i = 0; i < 64; ++i) {
            float a = cb;
            #pragma unroll
            for (int k = 0; k < DOBJ; ++k) a += MIL[i * 40 + k] * cw[k];
            short h = f2b(fmaxf(a, 0.f));
            A[i * 264 + t] = h;
            mi_out[(r0 + i) * 256 + t] = h;
        }
    }
    __syncthreads();

    const f32x4 Z4 = {0.f, 0.f, 0.f, 0.f};
    f32x4 acc[4][4];

    // v = mi @ Vw^T
    #pragma unroll
    for (int rt = 0; rt < 4; ++rt)
        #pragma unroll
        for (int nt = 0; nt < 4; ++nt) acc[rt][nt] = Z4;
    #pragma unroll
    for (int kt = 0; kt < 8; ++kt) {
        bf16x8 a[4];
        #pragma unroll
        for (int rt = 0; rt < 4; ++rt)
            a[rt] = *(const bf16x8*)&A[(rt * 16 + lr) * 264 + kt * 32 + quad * 8];
        #pragma unroll
        for (int nt = 0; nt < 4; ++nt) {
            int n = wv * 64 + nt * 16 + lr;
            bf16x8 b = ld8(Vw, n * 256 + kt * 32 + quad * 8, F32);
            #pragma unroll
            for (int rt = 0; rt < 4; ++rt) acc[rt][nt] = MFMA16(a[rt], b, acc[rt][nt]);
        }
    }
    __syncthreads();
    #pragma unroll
    for (int nt = 0; nt < 4; ++nt) {
        int n = wv * 64 + nt * 16 + lr;
        float vb = VBL[n];
        #pragma unroll
        for (int rt = 0; rt < 4; ++rt)
            #pragma unroll
            for (int r = 0; r < 4; ++r)
                A[(rt * 16 + quad * 4 + r) * 264 + n] = f2b(fmaxf(acc[rt][nt][r] + vb, 0.f));
    }
    __syncthreads();

    // jv = relu_v @ J2^T (J2 = Jw[:,256:512])
    #pragma unroll
    for (int rt = 0; rt < 4; ++rt)
        #pragma unroll
        for (int nt = 0; nt < 4; ++nt) acc[rt][nt] = Z4;
    #pragma unroll
    for (int kt = 0; kt < 8; ++kt) {
        bf16x8 a[4];
        #pragma unroll
        for (int rt = 0; rt < 4; ++rt)
            a[rt] = *(const bf16x8*)&A[(rt * 16 + lr) * 264 + kt * 32 + quad * 8];
        #pragma unroll
        for (int nt = 0; nt < 4; ++nt) {
            int n = wv * 64 + nt * 16 + lr;
            bf16x8 b = ld8(Jw, n * 768 + 256 + kt * 32 + quad * 8, F32);
            #pragma unroll
            for (int rt = 0; rt < 4; ++rt) acc[rt][nt] = MFMA16(a[rt], b, acc[rt][nt]);
        }
    }
    __syncthreads();
    #pragma unroll
    for (int nt = 0; nt < 4; ++nt) {
        int n = wv * 64 + nt * 16 + lr;
        #pragma unroll
        for (int rt = 0; rt < 4; ++rt)
            #pragma unroll
            for (int r = 0; r < 4; ++r)
                A[(rt * 16 + quad * 4 + r) * 264 + n] = f2b(acc[rt][nt][r]);
    }
    __syncthreads();
    for (int c = 0; c < 16; ++c) {
        int idx = c * 1024 + t * 4;
        int i = idx >> 8, k = idx & 255;
        *(ushort4*)&jv_out[(r0 + i) * 256 + k] = *(const ushort4*)&A[i * 264 + k];
    }
}

// ---------------------------------------------------------------------------
// Recurrence + head. grid 512 x 1024 thr (16 waves), 2 batches/WG.
// LDS 64416 B:
//   A1 [60*264] rows 0..39 mem RAW, 40..59 keys; pad per row:
//       shorts 256-257 = RS parity 0 (f32), 258-259 = RS parity 1 (f32),
//       shorts 260-263 = gate logits (2 f32, [bi]) -- mem logits pre-scaled
//   STG[40*264] relu(u*sc+Ub) restage + head scratch
//   SJ [ 2*264] sentence (mi) rows for the 2 batches
//   JWL[20*264] key-path J contribution + Jb, [slot][col] bf16
// ---------------------------------------------------------------------------
__global__ __launch_bounds__(1024) void renet_recur(
    const short* __restrict__ mi, const short* __restrict__ jv,
    const void* __restrict__ Qin, const void* __restrict__ Qw, const void* __restrict__ Qb,
    const void* __restrict__ Uw, const void* __restrict__ Ub,
    const void* __restrict__ Jw, const void* __restrict__ Jb,
    const void* __restrict__ Ww, const void* __restrict__ Wb,
    const void* __restrict__ Hw, const void* __restrict__ Hb,
    const void* __restrict__ PA, const void* __restrict__ Emb, void* __restrict__ Out)
{
    const bool F32 = (*(const unsigned*)PA == 0x3F800000u);
    __shared__ __align__(16) short LDS[32208];    // 64416 B
    short* const A1  = LDS;            // 60*264 = 15840 shorts
    short* const STG = LDS + 15840;    // 40*264 = 10560
    short* const SJ  = LDS + 26400;    //  2*264 =   528
    short* const JWL = LDS + 26928;    // 20*264 =  5280  (end 32208)

    const int t = threadIdx.x;                 // 0..1023
    const int w16 = t >> 6;                    // wave 0..15
    const int lane = t & 63, lr = lane & 15, quad = lane >> 4;
    const int colb = w16 * 16;                 // this wave's 16-col slice
    const int col4 = colb + quad * 4;          // lane's 4-col group
    const float pa = ld1(PA, 0, F32);
    const f32x4 Z4 = {0.f, 0.f, 0.f, 0.f};
    const int bq0 = blockIdx.x * 2;

    float ub2[4];
    #pragma unroll
    for (int r = 0; r < 4; ++r) ub2[r] = ld1(Ub, col4 + r, F32);

    // resident weight fragments (A-operand layout, lane lr = weight row)
    bf16x8 uf[8], jf[8];
    #pragma unroll
    for (int kt = 0; kt < 8; ++kt) {
        uf[kt] = ld8(Uw, (colb + lr) * 256 + kt * 32 + quad * 8, F32);
        jf[kt] = ld8(Jw, (colb + lr) * 768 + kt * 32 + quad * 8, F32);
    }

    // keys -> A1 rows 40..59 (pads zeroed)
    for (int c = 0; c < 6; ++c) {
        int idx = c * 1024 + t;
        if (idx < 20 * 264) {
            int row = idx / 264, k = idx - row * 264;
            A1[(40 + row) * 264 + k] = (k < 256) ? f2b(ld1(Emb, row * 256 + k, F32)) : (short)0;
        }
    }
    __syncthreads();

    // WKS = relu(Emb@Ww^T+Wb) (f32 in STG)
    {
        const int col = t & 255, grp = t >> 8, m0p = grp * 5;
        float* WKS = (float*)STG;
        float wacc[5] = {0.f, 0.f, 0.f, 0.f, 0.f};
        for (int c = 0; c < 32; ++c) {
            bf16x8 wv8 = ld8(Ww, col * 256 + c * 8, F32);
            float wf[8];
            #pragma unroll
            for (int e = 0; e < 8; ++e) wf[e] = b2f(wv8[e]);
            #pragma unroll
            for (int mm = 0; mm < 5; ++mm) {
                bf16x8 e8 = *(const bf16x8*)&A1[(40 + m0p + mm) * 264 + c * 8];
                float s = 0.f;
                #pragma unroll
                for (int e = 0; e < 8; ++e) s += b2f(e8[e]) * wf[e];
                wacc[mm] += s;
            }
        }
        float wb = ld1(Wb, col, F32);
        #pragma unroll
        for (int mm = 0; mm < 5; ++mm) WKS[(m0p + mm) * 256 + col] = fmaxf(wacc[mm] + wb, 0.f);
    }
    // mem rows 0..39 = keys raw; RS par0 := 1.0 (step 0 uses raw keys,
    // reference normalizes only AFTER the first update); RS par1 := 0
    for (int c = 0; c < 11; ++c) {
        int idx = c * 1024 + t;
        if (idx < 40 * 264) {
            int row = idx / 264, k = idx - row * 264;
            short v = (k < 256) ? A1[(40 + row % 20) * 264 + k] : (short)0;
            if (k == 256 || k == 257) v = (k == 257) ? (short)0x3F80 : (short)0;  // 1.0f LE halves
            A1[idx] = v;
        }
    }
    __syncthreads();

    // JWL[slot][col] = (WKS @ J3^T)[slot][col] + Jb[col]
    {
        const int col = t & 255, grp = t >> 8, m0p = grp * 5;
        const float* WKS = (const float*)STG;
        const float jb = ld1(Jb, col, F32);
        float jacc[5] = {0.f, 0.f, 0.f, 0.f, 0.f};
        for (int c = 0; c < 32; ++c) {
            bf16x8 j8 = ld8(Jw, col * 768 + 512 + c * 8, F32);
            float jfv[8];
            #pragma unroll
            for (int e = 0; e < 8; ++e) jfv[e] = b2f(j8[e]);
            #pragma unroll
            for (int mm = 0; mm < 5; ++mm) {
                float4 w0 = *(const float4*)&WKS[(m0p + mm) * 256 + c * 8];
                float4 w1 = *(const float4*)&WKS[(m0p + mm) * 256 + c * 8 + 4];
                jacc[mm] += w0.x * jfv[0] + w0.y * jfv[1] + w0.z * jfv[2] + w0.w * jfv[3]
                          + w1.x * jfv[4] + w1.y * jfv[5] + w1.z * jfv[6] + w1.w * jfv[7];
            }
        }
        #pragma unroll
        for (int mm = 0; mm < 5; ++mm) JWL[(m0p + mm) * 264 + col] = f2b(jacc[mm] + jb);
    }

    // stage sentence s=0
    ushort4 pf_mi = {0, 0, 0, 0};
    if (t < 128) {
        pf_mi = *(const ushort4*)&mi[(bq0 + (t >> 6)) * 256 + (t & 63) * 4];
        *(ushort4*)&SJ[(t >> 6) * 264 + (t & 63) * 4] = pf_mi;
    }
    __syncthreads();

    for (int s = 0; s < S_LEN; ++s) {
        const int parO = (s & 1) << 1, parN = 2 - parO;   // short-offsets 0 / 2

        // prefetch next sentence
        if (s + 1 < S_LEN && t < 128)
            pf_mi = *(const ushort4*)&mi[((s + 1) * BSZ + bq0 + (t >> 6)) * 256 + (t & 63) * 4];

        // sc_old per tile (row = base+lr)
        float sc_o[3];
        #pragma unroll
        for (int nt = 0; nt < 3; ++nt) {
            const int row = ((nt == 0) ? 0 : (nt == 1) ? 16 : 24) + lr;
            sc_o[nt] = 1.f / (sqrtf(*(const float*)&A1[row * 264 + 256 + parO]) + 1e-12f);
        }

        // ---- gate: G^T = sent(A) x [mem;keys]^T(B), waves 0..3; scale mem logits
        if (w16 < 4) {
            const int base = (w16 == 3) ? 44 : w16 * 16;
            f32x4 ag = Z4;
            #pragma unroll
            for (int kt = 0; kt < 8; ++kt) {
                bf16x8 a = *(const bf16x8*)&SJ[lr * 264 + kt * 32 + quad * 8];   // rows>=2 garbage, discarded
                bf16x8 b = *(const bf16x8*)&A1[(base + lr) * 264 + kt * 32 + quad * 8];
                ag = MFMA16(a, b, ag);
            }
            if (quad == 0) {
                const int row = base + lr;
                float sg = 1.f;
                if (row < 40) sg = 1.f / (sqrtf(*(const float*)&A1[row * 264 + 256 + parO]) + 1e-12f);
                float* gl = (float*)&A1[row * 264 + 260];
                gl[0] = ag[0] * sg; gl[1] = ag[1] * sg;
            }
        }

        // ---- GEMM1 (transposed): u^T = U_slice(A) x mem_raw^T(B)
        f32x4 acc[3];
        acc[0] = Z4; acc[1] = Z4; acc[2] = Z4;
        #pragma unroll
        for (int kt = 0; kt < 8; ++kt) {
            bf16x8 b0 = *(const bf16x8*)&A1[(0 + lr) * 264 + kt * 32 + quad * 8];
            bf16x8 b1 = *(const bf16x8*)&A1[(16 + lr) * 264 + kt * 32 + quad * 8];
            bf16x8 b2 = *(const bf16x8*)&A1[(24 + lr) * 264 + kt * 32 + quad * 8];
            acc[0] = MFMA16(uf[kt], b0, acc[0]);
            acc[1] = MFMA16(uf[kt], b1, acc[1]);
            acc[2] = MFMA16(uf[kt], b2, acc[2]);
        }
        // restage relu(u*sc + Ub) -> STG
        #pragma unroll
        for (int nt = 0; nt < 3; ++nt) {
            const int base = (nt == 0) ? 0 : (nt == 1) ? 16 : 24;
            uint2 pk;
            pk.x = pkbf(fmaxf(acc[nt][0] * sc_o[nt] + ub2[0], 0.f),
                        fmaxf(acc[nt][1] * sc_o[nt] + ub2[1], 0.f));
            pk.y = pkbf(fmaxf(acc[nt][2] * sc_o[nt] + ub2[2], 0.f),
                        fmaxf(acc[nt][3] * sc_o[nt] + ub2[3], 0.f));
            *(uint2*)&STG[(base + lr) * 264 + col4] = pk;
        }
        if (t < 40) *(float*)&A1[t * 264 + 256 + parN] = 0.f;   // zero RS_new
        __syncthreads();                                        // B_a

        // ---- jv direct from global (L2-hot), both batches
        bf16x4 jv0 = *(const bf16x4*)&jv[(s * BSZ + bq0) * 256 + col4];
        bf16x4 jv1 = *(const bf16x4*)&jv[(s * BSZ + bq0 + 1) * 256 + col4];

        // ---- GEMM2 (transposed): jU^T = J1_slice(A) x relu_u^T(B)
        f32x4 acc2[3];
        acc2[0] = Z4; acc2[1] = Z4; acc2[2] = Z4;
        #pragma unroll
        for (int kt = 0; kt < 8; ++kt) {
            bf16x8 b0 = *(const bf16x8*)&STG[(0 + lr) * 264 + kt * 32 + quad * 8];
            bf16x8 b1 = *(const bf16x8*)&STG[(16 + lr) * 264 + kt * 32 + quad * 8];
            bf16x8 b2 = *(const bf16x8*)&STG[(24 + lr) * 264 + kt * 32 + quad * 8];
            acc2[0] = MFMA16(jf[kt], b0, acc2[0]);
            acc2[1] = MFMA16(jf[kt], b1, acc2[1]);
            acc2[2] = MFMA16(jf[kt], b2, acc2[2]);
        }

        // ---- epilogue GATHER: all LDS reads before any writes (dup rows 24-31!)
        float gate_[3];
        bf16x4 old_[3], jw_[3];
        #pragma unroll
        for (int nt = 0; nt < 3; ++nt) {
            const int base = (nt == 0) ? 0 : (nt == 1) ? 16 : 24;
            const int row = base + lr;
            const int bi = (row >= 20) ? 1 : 0;
            const int slot = row - bi * 20;
            float gp = ((const float*)&A1[row * 264 + 260])[bi]
                     + ((const float*)&A1[(40 + slot) * 264 + 260])[bi];
            gate_[nt] = 1.f / (1.f + __expf(-gp));
            jw_[nt]  = *(const bf16x4*)&JWL[slot * 264 + col4];
            old_[nt] = *(const bf16x4*)&A1[row * 264 + col4];
        }
        // ---- epilogue COMMIT: compute upd_raw, write raw mem + RS atomics
        #pragma unroll
        for (int nt = 0; nt < 3; ++nt) {
            const int base = (nt == 0) ? 0 : (nt == 1) ? 16 : 24;
            const int row = base + lr;
            const int bi = (row >= 20) ? 1 : 0;
            bf16x4 jv4 = bi ? jv1 : jv0;
            float u4[4];
            float ss = 0.f;
            #pragma unroll
            for (int r = 0; r < 4; ++r) {
                float j = acc2[nt][r] + b2f(jv4[r]) + b2f(jw_[nt][r]);
                float cand = j > 0.f ? j : pa * j;
                float u = b2f(old_[nt][r]) * sc_o[nt] + gate_[nt] * cand;
                u4[r] = u;
                ss += u * u;
            }
            uint2 pk;
            pk.x = pkbf(u4[0], u4[1]);
            pk.y = pkbf(u4[2], u4[3]);
            *(uint2*)&A1[row * 264 + col4] = pk;        // dup rows write identical bits
            ss += __shfl_xor(ss, 16);
            ss += __shfl_xor(ss, 32);
            if (quad == 0 && !(nt == 2 && lr < 8))
                atomicAdd((float*)&A1[row * 264 + 256 + parN], ss);
        }
        // stage next sentence (SJ unread in phase B)
        if (t < 128) *(ushort4*)&SJ[(t >> 6) * 264 + (t & 63) * 4] = pf_mi;
        __syncthreads();                                        // B_c
    }

    // ---------------- attention + output head (mem raw; final RS at parity 0) --
    float* SF = (float*)STG;  // QF[0..511] HC[512..1535] EN[1536..1575] AT[1576..1615]
    if (t < 512) {
        const int col = t & 255, bi = t >> 8;
        float a = ld1(Qb, col, F32);
        #pragma unroll
        for (int k = 0; k < QD; ++k)
            a += ld1(Qin, (bq0 + bi) * QD + k, F32) * ld1(Qw, col * QD + k, F32);
        SF[bi * 256 + col] = fmaxf(a, 0.f);
    }
    __syncthreads();
    if (t < 40) {
        int bi = t / 20;
        float e = 0.f;
        for (int c = 0; c < 32; ++c) {
            bf16x8 mv = *(const bf16x8*)&A1[t * 264 + c * 8];
            #pragma unroll
            for (int e8 = 0; e8 < 8; ++e8) e += b2f(mv[e8]) * SF[bi * 256 + c * 8 + e8];
        }
        float scf = 1.f / (sqrtf(*(const float*)&A1[t * 264 + 256]) + 1e-12f);
        SF[1536 + t] = e * scf;
    }
    __syncthreads();
    if (t < 2) {
        float mx = -1e30f;
        for (int m = 0; m < 20; ++m) mx = fmaxf(mx, SF[1536 + t * 20 + m]);
        float sm = 0.f, ex[20];
        for (int m = 0; m < 20; ++m) { ex[m] = __expf(SF[1536 + t * 20 + m] - mx); sm += ex[m]; }
        float inv = 1.f / sm;
        for (int m = 0; m < 20; ++m) {
            float scf = 1.f / (sqrtf(*(const float*)&A1[(t * 20 + m) * 264 + 256]) + 1e-12f);
            SF[1576 + t * 20 + m] = ex[m] * inv * scf;   // fold row-norm into attn weight
        }
    }
    __syncthreads();
    if (t < 512) {
        const int col = t & 255, bi = t >> 8;
        float a = 0.f;
        for (int m = 0; m < 20; ++m)
            a += SF[1576 + bi * 20 + m] * b2f(A1[(bi * 20 + m) * 264 + col]);
        SF[512 + bi * 512 + 256 + col] = a;
        SF[512 + bi * 512 + col] = SF[bi * 256 + col];
    }
    __syncthreads();
    if (t < 512) {
        const int col = t & 255, bi = t >> 8;
        float o = ld1(Hb, col, F32);
        for (int c = 0; c < 64; ++c) {
            bf16x8 hv = ld8(Hw, col * 512 + c * 8, F32);
            #pragma unroll
            for (int e8 = 0; e8 < 8; ++e8) o += b2f(hv[e8]) * SF[512 + bi * 512 + c * 8 + e8];
        }
        int oi = (bq0 + bi) * 256 + col;
        float v = fmaxf(o, 0.f);
        if (F32) ((float*)Out)[oi] = v; else ((short*)Out)[oi] = f2b(v);
    }
}

// ---------------------------------------------------------------------------
extern "C" void kernel_launch(void* const* d_in, const int* in_sizes, int n_in,
                              void* d_out, int out_size, void* d_ws, size_t ws_size,
                              hipStream_t stream) {
    (void)in_sizes; (void)n_in; (void)out_size; (void)ws_size;
    const void* MIp = d_in[0];
    const void* Qin = d_in[1];
    const void* Cw  = d_in[2];
    const void* Cb  = d_in[3];
    const void* Qw  = d_in[4];
    const void* Qb  = d_in[5];
    const void* Hw  = d_in[6];
    const void* Hb  = d_in[7];
    const void* Uw  = d_in[8];
    const void* Ub  = d_in[9];
    const void* Vw  = d_in[10];
    const void* Vb  = d_in[11];
    const void* Ww  = d_in[12];
    const void* Wb  = d_in[13];
    const void* Jw  = d_in[14];
    const void* Jb  = d_in[15];
    const void* PA  = d_in[16];
    const void* Emb = d_in[17];

    short* mi_ws = (short*)d_ws;                          // (S*B,256) bf16 = 64 MiB
    short* jv_ws = mi_ws + (size_t)S_LEN * BSZ * 256;     // (S*B,256) bf16 = 64 MiB

    renet_phase1<<<dim3(2048), dim3(256), 0, stream>>>(MIp, Cw, Cb, Vw, Vb, Jw, PA, mi_ws, jv_ws);
    renet_recur<<<dim3(512), dim3(1024), 0, stream>>>(mi_ws, jv_ws, Qin, Qw, Qb, Uw, Ub,
                                                      Jw, Jb, Ww, Wb, Hw, Hb, PA, Emb, d_out);
}